// Round 4
// baseline (228.945 us; speedup 1.0000x reference)
//
#include <hip/hip_runtime.h>
#include <hip/hip_bf16.h>

#define D_FEAT 64
#define OVF_CAP 65536

typedef unsigned int uint32;

__device__ inline float blo(uint32 u) { return __uint_as_float(u << 16); }
__device__ inline float bhi(uint32 u) { return __uint_as_float(u & 0xffff0000u); }
__device__ inline float dinv(int d) { return (d > 0) ? rsqrtf((float)d) : 0.0f; }

// ---- build: one thread per edge, direct padded-CSR via global atomics;
//      fused bf16 cast of x. 6250 blocks -> fully latency-hidden, unlike the
//      391-block multisplit pipelines (rounds 0-3, all ~latency-bound).
__global__ __launch_bounds__(256) void k_prep(const float2* __restrict__ x2,
                                              uint32* __restrict__ xb,
                                              const int* __restrict__ row,
                                              const int* __restrict__ col,
                                              int* __restrict__ deg,
                                              int* __restrict__ slots,
                                              int2* __restrict__ ovf,
                                              int* __restrict__ ovf_cnt,
                                              int nhalf, int E, int C) {
    const int t = blockIdx.x * blockDim.x + threadIdx.x;
    if (t < E) {
        int c = col[t];
        int r = row[t];
        int rk = atomicAdd(&deg[c], 1);          // exact degree (counts all edges)
        if (rk < C) {
            slots[(size_t)c * C + rk] = r;
        } else {
            int o = atomicAdd(ovf_cnt, 1);
            if (o < OVF_CAP) ovf[o] = make_int2(r, c);
        }
    }
    // fused bf16 cast, node-major linear (xb[node] = 32 contiguous uint32)
    const int stride = gridDim.x * blockDim.x;
    for (int j = t; j < nhalf; j += stride) {
        float2 v = x2[j];
        __hip_bfloat16 bx = __float2bfloat16(v.x);
        __hip_bfloat16 by = __float2bfloat16(v.y);
        uint32 ux = *reinterpret_cast<unsigned short*>(&bx);
        uint32 uy = *reinterpret_cast<unsigned short*>(&by);
        xb[j] = ux | (uy << 16);
    }
}

// ---- gather: one wave per node, 4 edges in parallel, 16-edge unroll ----
// (round-0 verified body: 60 us, ~3.4 TB/s random-128B fetch)
__global__ void k_gather4(const uint32* __restrict__ xb,
                          const float4* __restrict__ x4,
                          const int* __restrict__ deg,
                          const int* __restrict__ slots,
                          const float* __restrict__ alpha_p,
                          const float* __restrict__ rs_p,
                          float4* __restrict__ out4, int n, int C) {
    int wid = (blockIdx.x * blockDim.x + threadIdx.x) >> 6;
    if (wid >= n) return;
    const int lane = threadIdx.x & 63;
    const int q = lane >> 4;
    const int l = lane & 15;
    int d = deg[wid];
    int e = (d < C) ? d : C;
    float4 xr = make_float4(0.f, 0.f, 0.f, 0.f);
    if (q == 0) xr = x4[(size_t)wid * 16 + l];   // hoisted residual load
    const int* sl = slots + (size_t)wid * C;
    float ax = 0.f, ay = 0.f, az = 0.f, aw = 0.f;
    int k = 0;
    for (; k + 16 <= e; k += 16) {
        int s0 = sl[k + q];
        int s1 = sl[k + 4 + q];
        int s2 = sl[k + 8 + q];
        int s3 = sl[k + 12 + q];
        int d0 = deg[s0], d1 = deg[s1], d2 = deg[s2], d3 = deg[s3];
        uint2 p0 = ((const uint2*)(xb + (size_t)s0 * 32))[l];
        uint2 p1 = ((const uint2*)(xb + (size_t)s1 * 32))[l];
        uint2 p2 = ((const uint2*)(xb + (size_t)s2 * 32))[l];
        uint2 p3 = ((const uint2*)(xb + (size_t)s3 * 32))[l];
        float w0 = dinv(d0), w1 = dinv(d1), w2 = dinv(d2), w3 = dinv(d3);
        ax = fmaf(w0, blo(p0.x), ax); ay = fmaf(w0, bhi(p0.x), ay);
        az = fmaf(w0, blo(p0.y), az); aw = fmaf(w0, bhi(p0.y), aw);
        ax = fmaf(w1, blo(p1.x), ax); ay = fmaf(w1, bhi(p1.x), ay);
        az = fmaf(w1, blo(p1.y), az); aw = fmaf(w1, bhi(p1.y), aw);
        ax = fmaf(w2, blo(p2.x), ax); ay = fmaf(w2, bhi(p2.x), ay);
        az = fmaf(w2, blo(p2.y), az); aw = fmaf(w2, bhi(p2.y), aw);
        ax = fmaf(w3, blo(p3.x), ax); ay = fmaf(w3, bhi(p3.x), ay);
        az = fmaf(w3, blo(p3.y), az); aw = fmaf(w3, bhi(p3.y), aw);
    }
    for (; k < e; k += 4) {
        int kk = k + q;
        if (kk < e) {
            int s0 = sl[kk];
            float w0 = dinv(deg[s0]);
            uint2 p0 = ((const uint2*)(xb + (size_t)s0 * 32))[l];
            ax = fmaf(w0, blo(p0.x), ax); ay = fmaf(w0, bhi(p0.x), ay);
            az = fmaf(w0, blo(p0.y), az); aw = fmaf(w0, bhi(p0.y), aw);
        }
    }
    ax += __shfl_down(ax, 32, 64); ay += __shfl_down(ay, 32, 64);
    az += __shfl_down(az, 32, 64); aw += __shfl_down(aw, 32, 64);
    ax += __shfl_down(ax, 16, 64); ay += __shfl_down(ay, 16, 64);
    az += __shfl_down(az, 16, 64); aw += __shfl_down(aw, 16, 64);
    if (q == 0) {
        float adw = (*alpha_p) * dinv(d);
        float rs  = *rs_p;
        float4 o;
        o.x = fmaf(adw, ax, rs * xr.x);
        o.y = fmaf(adw, ay, rs * xr.y);
        o.z = fmaf(adw, az, rs * xr.z);
        o.w = fmaf(adw, aw, rs * xr.w);
        out4[(size_t)wid * 16 + l] = o;
    }
}

// ---- overflow fix-up (deg>C only; rare): fp32 exact ----
__global__ void k_ovf(const int2* __restrict__ ovf, const int* __restrict__ cnt_p,
                      const float* __restrict__ x, const int* __restrict__ deg,
                      const float* __restrict__ alpha_p, float* __restrict__ out) {
    int cnt = *cnt_p;
    if (cnt > OVF_CAP) cnt = OVF_CAP;
    if (cnt <= 0) return;
    float a = *alpha_p;
    long long total = (long long)cnt * 64;
    long long stride = (long long)gridDim.x * blockDim.x;
    for (long long idx = blockIdx.x * (long long)blockDim.x + threadIdx.x;
         idx < total; idx += stride) {
        int e = (int)(idx >> 6);
        int f = (int)(idx & 63);
        int2 rc = ovf[e];
        float w = a * dinv(deg[rc.x]) * dinv(deg[rc.y]);
        atomicAdd(&out[(size_t)rc.y * D_FEAT + f], w * x[(size_t)rc.x * D_FEAT + f]);
    }
}

static inline char* align_up(char* p, size_t a) {
    return (char*)(((uintptr_t)p + (a - 1)) & ~(uintptr_t)(a - 1));
}

extern "C" void kernel_launch(void* const* d_in, const int* in_sizes, int n_in,
                              void* d_out, int out_size, void* d_ws, size_t ws_size,
                              hipStream_t stream) {
    const float* x         = (const float*)d_in[0];
    const float* alpha     = (const float*)d_in[1];
    const float* res_scale = (const float*)d_in[2];
    const int*   ei        = (const int*)d_in[3];

    const int n = in_sizes[0] / D_FEAT;      // 100000
    const int E = in_sizes[3] / 2;           // 1600000
    const int* row = ei;                     // sources
    const int* col = ei + E;                 // targets

    float* out = (float*)d_out;
    const int nhalf = n * (D_FEAT / 2);

    char* p = (char*)d_ws;
    int*    deg     = (int*)p;            p += (size_t)n * 4;
    int*    ovf_cnt = (int*)p;            p += 4;
    int2*   ovf     = (int2*)p;           p += (size_t)OVF_CAP * 8;
    p = align_up(p, 16);
    uint32* xb      = (uint32*)p;         p += (size_t)n * 128;
    int*    slots   = (int*)p;
    const size_t fixed = (size_t)(p - (char*)d_ws);

    int C = 0;
    if (ws_size > fixed) {
        size_t c_avail = (ws_size - fixed) / ((size_t)n * 4);
        C = (c_avail > 32) ? 32 : (int)c_avail;
    }
    if (C < 1) return;  // ws too small for anything sane

    // zero deg + ovf_cnt (contiguous)
    hipMemsetAsync(deg, 0, (size_t)n * 4 + 4, stream);
    k_prep<<<(E + 255) / 256, 256, 0, stream>>>(
        (const float2*)x, xb, row, col, deg, slots, ovf, ovf_cnt,
        nhalf, E, C);
    const long long tt = (long long)n * D_FEAT;
    const int blocks = (int)((tt + 255) / 256);
    k_gather4<<<blocks, 256, 0, stream>>>(xb, (const float4*)x, deg, slots,
                                          alpha, res_scale, (float4*)out, n, C);
    k_ovf<<<64, 256, 0, stream>>>(ovf, ovf_cnt, x, deg, alpha, out);
}